// Round 17
// baseline (453.785 us; speedup 1.0000x reference)
//
#include <hip/hip_runtime.h>
#include <math.h>

// ---------------------------------------------------------------------------
// B=16, T=4096, D=256, V=256, PATCH=4, Np=1024, BN=16384
// All GEMMs: C[M,N] = A[M,256] @ Bt[N,256]^T (+epilogue), bf16 inputs.
// LDS tiles XOR-swizzled (T2). GRU steps 1-3 fully fused (3-panel GEMM +
// gate epilogue, H ping-pong). Sparse top-8 attention: bf16 scores GEMM +
// u64-key scan. MP round: K=512 dual-A GEMM + fused GEMM-LN.
// ---------------------------------------------------------------------------

typedef __bf16 bf16_t;
typedef bf16_t bf16x8 __attribute__((ext_vector_type(8)));
typedef bf16_t bf16x4 __attribute__((ext_vector_type(4)));
typedef float f32x4 __attribute__((ext_vector_type(4)));

#define GF_BIAS 1
#define GF_GELU 4
#define GF_RES 8
#define GF_F32OUT 32

__device__ __forceinline__ float gelu_exact(float x) {
  return 0.5f * x * (1.0f + erff(x * 0.7071067811865475f));
}

__device__ __forceinline__ float sigm(float x) { return 1.f / (1.f + expf(-x)); }

__device__ __forceinline__ float wave_sum(float v) {
#pragma unroll
  for (int o = 32; o; o >>= 1) v += __shfl_xor(v, o, 64);
  return v;
}

__device__ __forceinline__ void gload16(const void* g, void* l) {
  __builtin_amdgcn_global_load_lds(
      (const __attribute__((address_space(1))) void*)g,
      (__attribute__((address_space(3))) void*)l, 16, 0, 0);
}

// sortable u64 key: (order-preserving f32 map) << 32 | (0x7FFFFFFF - m)
// larger key == (larger score, then lower index). Key 0 == empty slot.
__device__ __forceinline__ unsigned long long skey(float s, int m) {
  unsigned u = __float_as_uint(s);
  u ^= (u & 0x80000000u) ? 0xFFFFFFFFu : 0x80000000u;
  return ((unsigned long long)u << 32) | (unsigned)(0x7FFFFFFF - m);
}

// ---------------- bf16 MFMA GEMM: 128x128 tile, 4 waves, BK=64, swizzled ----
template<int FLAGS>
__global__ __launch_bounds__(256)
void gemm_bt(const bf16_t* __restrict__ A, const bf16_t* __restrict__ Bt,
             void* __restrict__ Cv, const float* __restrict__ bias,
             const bf16_t* __restrict__ res,
             int lda, int ldb, int ldc, int ldr)
{
  __shared__ __align__(16) bf16_t As[128][64];
  __shared__ __align__(16) bf16_t Bs[128][64];
  const int m0 = blockIdx.x * 128, n0 = blockIdx.y * 128;
  const int tid = threadIdx.x, lane = tid & 63, wave = tid >> 6;
  const int wm = (wave >> 1) << 6, wn = (wave & 1) << 6;
  const int lr = lane & 15, lg = lane >> 4;
  const int cx = lane & 7;

  const int srow = wave * 32 + (lane >> 3);
  const int scol = (((lane & 7) ^ ((lane >> 3) & 7)) * 8);
  const bf16_t* ga = A  + (long long)(m0 + srow) * lda + scol;
  const bf16_t* gb = Bt + (long long)(n0 + srow) * ldb + scol;
  char* lA = (char*)(&As[srow][0]) + (lane & 7) * 16;
  char* lB = (char*)(&Bs[srow][0]) + (lane & 7) * 16;

  f32x4 acc[4][4] = {};

#pragma unroll
  for (int kt = 0; kt < 4; kt++) {
    const int ko = kt * 64;
#pragma unroll
    for (int q = 0; q < 4; q++) {
      gload16(ga + (long long)q * 8 * lda + ko, lA + q * 1024);
      gload16(gb + (long long)q * 8 * ldb + ko, lB + q * 1024);
    }
    __syncthreads();
#pragma unroll
    for (int kk = 0; kk < 2; kk++) {
      const int co = ((kk * 4 + lg) ^ cx) << 4;
      bf16x8 af[4], bfv[4];
#pragma unroll
      for (int i = 0; i < 4; i++)
        af[i]  = *(const bf16x8*)((char*)As + (wm + i * 16 + lr) * 128 + co);
#pragma unroll
      for (int j = 0; j < 4; j++)
        bfv[j] = *(const bf16x8*)((char*)Bs + (wn + j * 16 + lr) * 128 + co);
#pragma unroll
      for (int i = 0; i < 4; i++)
#pragma unroll
        for (int j = 0; j < 4; j++)
          acc[i][j] = __builtin_amdgcn_mfma_f32_16x16x32_bf16(af[i], bfv[j], acc[i][j], 0, 0, 0);
    }
    if (kt < 3) __syncthreads();
  }

#pragma unroll
  for (int i = 0; i < 4; i++) {
#pragma unroll
    for (int j = 0; j < 4; j++) {
      const int col = n0 + wn + j * 16 + lr;
      const float bval = (FLAGS & GF_BIAS) ? bias[col] : 0.f;
#pragma unroll
      for (int e = 0; e < 4; e++) {
        const int row = m0 + wm + i * 16 + lg * 4 + e;
        float v = acc[i][j][e] + bval;
        if (FLAGS & GF_RES) v += (float)res[(long long)row * ldr + col];
        if (FLAGS & GF_GELU) v = gelu_exact(v);
        const long long ci = (long long)row * ldc + col;
        if (FLAGS & GF_F32OUT) ((float*)Cv)[ci] = v;
        else                   ((bf16_t*)Cv)[ci] = (bf16_t)v;
      }
    }
  }
}

// ---------------- fused GRU step: 3-panel GEMM + gate epilogue --------------
// Block (m, dblk): rows m0..m0+63, d-cols d0..d0+127. Stages WHHT panels
// {d, 256+d, 512+d} (48KB) + Hin tile; epilogue computes GRU gates with
// GITAB gathers and writes Hout/LOC. Hin/Hout ping-pong avoids races.
__global__ __launch_bounds__(256)
void k_gru_fused(const int* __restrict__ x, const bf16_t* __restrict__ gitab,
                 const bf16_t* __restrict__ WHHT, const float* __restrict__ bhh,
                 const bf16_t* __restrict__ Hin, bf16_t* __restrict__ Hout,
                 bf16_t* __restrict__ LOC, int t)
{
  __shared__ __align__(16) bf16_t As[64][64];
  __shared__ __align__(16) bf16_t Bs[3][128][64];
  const int m0 = blockIdx.x * 64;
  const int d0 = blockIdx.y * 128;
  const int tid = threadIdx.x, lane = tid & 63, wave = tid >> 6;
  const int wrow = (wave >> 1) * 32, wcol = (wave & 1) * 64;
  const int lr = lane & 15, lg = lane >> 4, cx = lane & 7;

  f32x4 acc[3][2][4] = {};

#pragma unroll
  for (int kt = 0; kt < 4; kt++) {
    const int ko = kt * 64;
#pragma unroll
    for (int it = 0; it < 2; it++) {
      const int lin = it * 256 + tid, r = lin >> 3, cb = lin & 7;
      gload16(Hin + (long long)(m0 + r) * 256 + ko + ((cb ^ (r & 7)) * 8),
              (char*)As + lin * 16);
    }
#pragma unroll
    for (int it = 0; it < 12; it++) {
      const int lin = it * 256 + tid;
      const int p = lin >> 10, rem = lin & 1023;
      const int r = rem >> 3, cb = rem & 7;
      gload16(WHHT + (long long)(p * 256 + d0 + r) * 256 + ko + ((cb ^ (r & 7)) * 8),
              (char*)Bs + lin * 16);
    }
    __syncthreads();
#pragma unroll
    for (int kk = 0; kk < 2; kk++) {
      const int co = ((kk * 4 + lg) ^ cx) << 4;
      bf16x8 af[2];
#pragma unroll
      for (int i = 0; i < 2; i++)
        af[i] = *(const bf16x8*)((char*)As + (wrow + i * 16 + lr) * 128 + co);
#pragma unroll
      for (int p = 0; p < 3; p++) {
        bf16x8 bf[4];
#pragma unroll
        for (int j = 0; j < 4; j++)
          bf[j] = *(const bf16x8*)((char*)Bs + p * 16384 + (wcol + j * 16 + lr) * 128 + co);
#pragma unroll
        for (int i = 0; i < 2; i++)
#pragma unroll
          for (int j = 0; j < 4; j++)
            acc[p][i][j] = __builtin_amdgcn_mfma_f32_16x16x32_bf16(af[i], bf[j], acc[p][i][j], 0, 0, 0);
      }
    }
    if (kt < 3) __syncthreads();
  }

  // gate epilogue
#pragma unroll
  for (int i = 0; i < 2; i++) {
#pragma unroll
    for (int e = 0; e < 4; e++) {
      const int row = m0 + wrow + i * 16 + lg * 4 + e;
      const int v = x[row * 4 + t];
      const bf16_t* gi = gitab + (long long)(t * 256 + v) * 768;
#pragma unroll
      for (int j = 0; j < 4; j++) {
        const int c = d0 + wcol + j * 16 + lr;
        const float gr = acc[0][i][j][e] + bhh[c];
        const float gz = acc[1][i][j][e] + bhh[256 + c];
        const float gn = acc[2][i][j][e] + bhh[512 + c];
        const float rr = sigm((float)gi[c] + gr);
        const float zz = sigm((float)gi[256 + c] + gz);
        const float nn = tanhf((float)gi[512 + c] + rr * gn);
        const float h = (1.f - zz) * nn + zz * (float)Hin[(long long)row * 256 + c];
        Hout[(long long)row * 256 + c] = (bf16_t)h;
        LOC[((long long)row * 4 + t) * 256 + c] = (bf16_t)h;
      }
    }
  }
}

// ---------------- causal scores GEMM: z-batched, scaled, masked, bf16 -------
__global__ __launch_bounds__(256)
void gemm_sc(const bf16_t* __restrict__ Qb, const bf16_t* __restrict__ Kb,
             bf16_t* __restrict__ S)
{
  __shared__ __align__(16) bf16_t As[128][64];
  __shared__ __align__(16) bf16_t Bs[128][64];
  const int z = blockIdx.z;
  const int m0 = blockIdx.x * 128, n0 = blockIdx.y * 128;
  if (n0 > m0) return;  // tile fully above diagonal
  const bf16_t* A  = Qb + (long long)z * (1024LL * 768);
  const bf16_t* Bt = Kb + (long long)z * (1024LL * 768);
  bf16_t* C = S + (long long)z * (1024LL * 1024);
  const int tid = threadIdx.x, lane = tid & 63, wave = tid >> 6;
  const int wm = (wave >> 1) << 6, wn = (wave & 1) << 6;
  const int lr = lane & 15, lg = lane >> 4;
  const int cx = lane & 7;

  const int srow = wave * 32 + (lane >> 3);
  const int scol = (((lane & 7) ^ ((lane >> 3) & 7)) * 8);
  const bf16_t* ga = A  + (long long)(m0 + srow) * 768 + scol;
  const bf16_t* gb = Bt + (long long)(n0 + srow) * 768 + scol;
  char* lA = (char*)(&As[srow][0]) + (lane & 7) * 16;
  char* lB = (char*)(&Bs[srow][0]) + (lane & 7) * 16;

  f32x4 acc[4][4] = {};

#pragma unroll
  for (int kt = 0; kt < 4; kt++) {
    const int ko = kt * 64;
#pragma unroll
    for (int q = 0; q < 4; q++) {
      gload16(ga + (long long)q * 8 * 768 + ko, lA + q * 1024);
      gload16(gb + (long long)q * 8 * 768 + ko, lB + q * 1024);
    }
    __syncthreads();
#pragma unroll
    for (int kk = 0; kk < 2; kk++) {
      const int co = ((kk * 4 + lg) ^ cx) << 4;
      bf16x8 af[4], bfv[4];
#pragma unroll
      for (int i = 0; i < 4; i++)
        af[i]  = *(const bf16x8*)((char*)As + (wm + i * 16 + lr) * 128 + co);
#pragma unroll
      for (int j = 0; j < 4; j++)
        bfv[j] = *(const bf16x8*)((char*)Bs + (wn + j * 16 + lr) * 128 + co);
#pragma unroll
      for (int i = 0; i < 4; i++)
#pragma unroll
        for (int j = 0; j < 4; j++)
          acc[i][j] = __builtin_amdgcn_mfma_f32_16x16x32_bf16(af[i], bfv[j], acc[i][j], 0, 0, 0);
    }
    if (kt < 3) __syncthreads();
  }

#pragma unroll
  for (int i = 0; i < 4; i++) {
#pragma unroll
    for (int j = 0; j < 4; j++) {
      const int col = n0 + wn + j * 16 + lr;
#pragma unroll
      for (int e = 0; e < 4; e++) {
        const int row = m0 + wm + i * 16 + lg * 4 + e;
        float v = acc[i][j][e] * 0.0625f;
        if (col > row) v = -__builtin_inff();
        C[(long long)row * 1024 + col] = (bf16_t)v;
      }
    }
  }
}

// ---------------- bf16 MFMA GEMM: 64x64 tile, 4 waves, BK=64, swizzled ------
template<int FLAGS>
__global__ __launch_bounds__(256)
void gemm64(const bf16_t* __restrict__ A, const bf16_t* __restrict__ Bt,
            void* __restrict__ Cv, const float* __restrict__ bias,
            const bf16_t* __restrict__ res,
            int lda, int ldb, int ldc, int ldr)
{
  __shared__ __align__(16) bf16_t As[64][64];
  __shared__ __align__(16) bf16_t Bs[64][64];
  const int m0 = blockIdx.x * 64, n0 = blockIdx.y * 64;
  const int tid = threadIdx.x, lane = tid & 63, wave = tid >> 6;
  const int wm = (wave >> 1) * 32, wn = (wave & 1) * 32;
  const int lr = lane & 15, lg = lane >> 4;
  const int cx = lane & 7;

  const int srow = tid >> 3;
  const int scol = (((tid & 7) ^ (srow & 7)) * 8);
  const bf16_t* ga = A  + (long long)(m0 + srow) * lda + scol;
  const bf16_t* gb = Bt + (long long)(n0 + srow) * ldb + scol;
  char* lA = (char*)As + tid * 16;
  char* lB = (char*)Bs + tid * 16;

  f32x4 acc[2][2] = {};

#pragma unroll
  for (int kt = 0; kt < 4; kt++) {
    const int ko = kt * 64;
    gload16(ga + ko, lA);
    gload16(ga + 32LL * lda + ko, lA + 4096);
    gload16(gb + ko, lB);
    gload16(gb + 32LL * ldb + ko, lB + 4096);
    __syncthreads();
#pragma unroll
    for (int kk = 0; kk < 2; kk++) {
      const int co = ((kk * 4 + lg) ^ cx) << 4;
      bf16x8 af[2], bfv[2];
#pragma unroll
      for (int i = 0; i < 2; i++)
        af[i]  = *(const bf16x8*)((char*)As + (wm + i * 16 + lr) * 128 + co);
#pragma unroll
      for (int j = 0; j < 2; j++)
        bfv[j] = *(const bf16x8*)((char*)Bs + (wn + j * 16 + lr) * 128 + co);
#pragma unroll
      for (int i = 0; i < 2; i++)
#pragma unroll
        for (int j = 0; j < 2; j++)
          acc[i][j] = __builtin_amdgcn_mfma_f32_16x16x32_bf16(af[i], bfv[j], acc[i][j], 0, 0, 0);
    }
    if (kt < 3) __syncthreads();
  }

#pragma unroll
  for (int i = 0; i < 2; i++) {
#pragma unroll
    for (int j = 0; j < 2; j++) {
      const int col = n0 + wn + j * 16 + lr;
      const float bval = (FLAGS & GF_BIAS) ? bias[col] : 0.f;
#pragma unroll
      for (int e = 0; e < 4; e++) {
        const int row = m0 + wm + i * 16 + lg * 4 + e;
        float v = acc[i][j][e] + bval;
        if (FLAGS & GF_RES) v += (float)res[(long long)row * ldr + col];
        if (FLAGS & GF_GELU) v = gelu_exact(v);
        const long long ci = (long long)row * ldc + col;
        if (FLAGS & GF_F32OUT) ((float*)Cv)[ci] = v;
        else                   ((bf16_t*)Cv)[ci] = (bf16_t)v;
      }
    }
  }
}

// ---------------- dual-A K=512 gemm64: C = gelu(A1@Bt1 + A2@Bt2 + bias) -----
__global__ __launch_bounds__(256)
void gemm64_k512(const bf16_t* __restrict__ A1, const bf16_t* __restrict__ A2,
                 const bf16_t* __restrict__ Bt1, const bf16_t* __restrict__ Bt2,
                 bf16_t* __restrict__ C, const float* __restrict__ bias)
{
  __shared__ __align__(16) bf16_t As[64][64];
  __shared__ __align__(16) bf16_t Bs[64][64];
  const int m0 = blockIdx.x * 64, n0 = blockIdx.y * 64;
  const int tid = threadIdx.x, lane = tid & 63, wave = tid >> 6;
  const int wm = (wave >> 1) * 32, wn = (wave & 1) * 32;
  const int lr = lane & 15, lg = lane >> 4;
  const int cx = lane & 7;

  const int srow = tid >> 3;
  const int scol = (((tid & 7) ^ (srow & 7)) * 8);
  char* lA = (char*)As + tid * 16;
  char* lB = (char*)Bs + tid * 16;

  f32x4 acc[2][2] = {};

#pragma unroll
  for (int kt = 0; kt < 8; kt++) {
    const bf16_t* Ap  = (kt < 4) ? A1 : A2;
    const bf16_t* Btp = (kt < 4) ? Bt1 : Bt2;
    const int ko = (kt & 3) * 64;
    const bf16_t* ga = Ap  + (long long)(m0 + srow) * 256 + scol + ko;
    const bf16_t* gb = Btp + (long long)(n0 + srow) * 256 + scol + ko;
    gload16(ga, lA);
    gload16(ga + 32LL * 256, lA + 4096);
    gload16(gb, lB);
    gload16(gb + 32LL * 256, lB + 4096);
    __syncthreads();
#pragma unroll
    for (int kk = 0; kk < 2; kk++) {
      const int co = ((kk * 4 + lg) ^ cx) << 4;
      bf16x8 af[2], bfv[2];
#pragma unroll
      for (int i = 0; i < 2; i++)
        af[i]  = *(const bf16x8*)((char*)As + (wm + i * 16 + lr) * 128 + co);
#pragma unroll
      for (int j = 0; j < 2; j++)
        bfv[j] = *(const bf16x8*)((char*)Bs + (wn + j * 16 + lr) * 128 + co);
#pragma unroll
      for (int i = 0; i < 2; i++)
#pragma unroll
        for (int j = 0; j < 2; j++)
          acc[i][j] = __builtin_amdgcn_mfma_f32_16x16x32_bf16(af[i], bfv[j], acc[i][j], 0, 0, 0);
    }
    if (kt < 7) __syncthreads();
  }

#pragma unroll
  for (int i = 0; i < 2; i++) {
#pragma unroll
    for (int j = 0; j < 2; j++) {
      const int col = n0 + wn + j * 16 + lr;
      const float bval = bias[col];
#pragma unroll
      for (int e = 0; e < 4; e++) {
        const int row = m0 + wm + i * 16 + lg * 4 + e;
        C[(long long)row * 256 + col] = (bf16_t)gelu_exact(acc[i][j][e] + bval);
      }
    }
  }
}

// ---------------- fused GEMM + LayerNorm (64 rows x full N=256) -------------
// MODE 0: C = LN(C + A@Bt + bias)           (in place on C, block-owned rows)
// MODE 1: OUTMP += (1-HP[b]) * LN(C + A@Bt + bias)   (C unchanged/dead)
template<int MODE>
__global__ __launch_bounds__(256)
void gemm_ln(const bf16_t* __restrict__ A, const bf16_t* __restrict__ Bt,
             bf16_t* __restrict__ C, const float* __restrict__ bias,
             const float* __restrict__ g, const float* __restrict__ bvec,
             bf16_t* __restrict__ OUTMP, const float* __restrict__ HP)
{
  __shared__ __align__(16) bf16_t As[64][64];
  __shared__ __align__(16) bf16_t Bs[256][64];
  __shared__ float redsum[4][64];
  __shared__ float redsq[4][64];
  const int m0 = blockIdx.x * 64;
  const int tid = threadIdx.x, lane = tid & 63, w = tid >> 6;
  const int lr = lane & 15, lg = lane >> 4, cx = lane & 7;

  f32x4 acc[4][4] = {};

#pragma unroll
  for (int kt = 0; kt < 4; kt++) {
    const int ko = kt * 64;
    {
      int cid = tid, r = cid >> 3, c = cid & 7;
      gload16(A + (long long)(m0 + r) * 256 + ko + ((c ^ (r & 7)) * 8), (char*)As + cid * 16);
      cid = tid + 256; r = cid >> 3; c = cid & 7;
      gload16(A + (long long)(m0 + r) * 256 + ko + ((c ^ (r & 7)) * 8), (char*)As + cid * 16);
    }
#pragma unroll
    for (int it = 0; it < 8; it++) {
      const int cid = it * 256 + tid, r = cid >> 3, c = cid & 7;
      gload16(Bt + (long long)r * 256 + ko + ((c ^ (r & 7)) * 8), (char*)Bs + cid * 16);
    }
    __syncthreads();
#pragma unroll
    for (int kk = 0; kk < 2; kk++) {
      const int co = ((kk * 4 + lg) ^ cx) << 4;
      bf16x8 af[4], bfv[4];
#pragma unroll
      for (int i = 0; i < 4; i++)
        af[i]  = *(const bf16x8*)((char*)As + (i * 16 + lr) * 128 + co);
#pragma unroll
      for (int j = 0; j < 4; j++)
        bfv[j] = *(const bf16x8*)((char*)Bs + (w * 64 + j * 16 + lr) * 128 + co);
#pragma unroll
      for (int i = 0; i < 4; i++)
#pragma unroll
        for (int j = 0; j < 4; j++)
          acc[i][j] = __builtin_amdgcn_mfma_f32_16x16x32_bf16(af[i], bfv[j], acc[i][j], 0, 0, 0);
    }
    if (kt < 3) __syncthreads();
  }

  float v[4][4][4];
  float rs[4][4], rq[4][4];
#pragma unroll
  for (int i = 0; i < 4; i++) {
#pragma unroll
    for (int e = 0; e < 4; e++) { rs[i][e] = 0.f; rq[i][e] = 0.f; }
  }
#pragma unroll
  for (int i = 0; i < 4; i++) {
#pragma unroll
    for (int j = 0; j < 4; j++) {
      const int col = w * 64 + j * 16 + lr;
      const float bval = bias[col];
#pragma unroll
      for (int e = 0; e < 4; e++) {
        const long long rg = m0 + i * 16 + lg * 4 + e;
        const float val = acc[i][j][e] + bval + (float)C[rg * 256 + col];
        v[i][j][e] = val;
        rs[i][e] += val;
        rq[i][e] += val * val;
      }
    }
  }
#pragma unroll
  for (int off = 1; off < 16; off <<= 1) {
#pragma unroll
    for (int i = 0; i < 4; i++)
#pragma unroll
      for (int e = 0; e < 4; e++) {
        rs[i][e] += __shfl_xor(rs[i][e], off, 64);
        rq[i][e] += __shfl_xor(rq[i][e], off, 64);
      }
  }
  if (lr == 0) {
#pragma unroll
    for (int i = 0; i < 4; i++)
#pragma unroll
      for (int e = 0; e < 4; e++) {
        redsum[w][i * 16 + lg * 4 + e] = rs[i][e];
        redsq[w][i * 16 + lg * 4 + e]  = rq[i][e];
      }
  }
  __syncthreads();
  float mean[4][4], rstd[4][4];
#pragma unroll
  for (int i = 0; i < 4; i++) {
#pragma unroll
    for (int e = 0; e < 4; e++) {
      const int r = i * 16 + lg * 4 + e;
      const float S = redsum[0][r] + redsum[1][r] + redsum[2][r] + redsum[3][r];
      const float Q = redsq[0][r] + redsq[1][r] + redsq[2][r] + redsq[3][r];
      const float m = S * (1.f / 256.f);
      float var = Q * (1.f / 256.f) - m * m;
      if (var < 0.f) var = 0.f;
      mean[i][e] = m;
      rstd[i][e] = rsqrtf(var + 1e-5f);
    }
  }
#pragma unroll
  for (int i = 0; i < 4; i++) {
#pragma unroll
    for (int j = 0; j < 4; j++) {
      const int col = w * 64 + j * 16 + lr;
      const float gg = g[col], bb = bvec[col];
#pragma unroll
      for (int e = 0; e < 4; e++) {
        const long long rg = m0 + i * 16 + lg * 4 + e;
        const float y = (v[i][j][e] - mean[i][e]) * rstd[i][e] * gg + bb;
        if (MODE == 0) {
          C[rg * 256 + col] = (bf16_t)y;
        } else {
          const float rem = 1.f - HP[(int)(rg >> 10)];
          OUTMP[rg * 256 + col] = (bf16_t)((float)OUTMP[rg * 256 + col] + rem * y);
        }
      }
    }
  }
}

// ---------------- top-8 causal sparse attention (bf16 scores, u64 keys) -----
__global__ __launch_bounds__(256)
void k_topk(const bf16_t* __restrict__ S, const bf16_t* __restrict__ QKV,
            bf16_t* __restrict__ O) {
  const int n = blockIdx.x * 4 + (threadIdx.x >> 6);
  const int b = blockIdx.y;
  const int lane = threadIdx.x & 63;
  const bf16_t* srow = S + ((long long)(b * 1024 + n)) * 1024;
  unsigned long long kv[8] = {0, 0, 0, 0, 0, 0, 0, 0};
  for (int mb = lane * 8; mb <= n; mb += 512) {
    const bf16x8 s8 = *(const bf16x8*)(srow + mb);
#pragma unroll
    for (int jj = 0; jj < 8; jj++) {
      const int m = mb + jj;
      if (m <= n) {
        const unsigned long long k = skey((float)s8[jj], m);
        if (k > kv[7]) {
          kv[7] = k;
#pragma unroll
          for (int j = 7; j > 0; j--) {
            if (kv[j] > kv[j-1]) {
              const unsigned long long t = kv[j]; kv[j] = kv[j-1]; kv[j-1] = t;
            }
          }
        }
      }
    }
  }
  // 8 rounds of wave-wide u64 max; winner lane pops its list head
  float wv[8]; int wi[8];
#pragma unroll
  for (int r = 0; r < 8; r++) {
    unsigned long long mk = kv[0];
#pragma unroll
    for (int off = 32; off; off >>= 1) {
      const unsigned long long ok = __shfl_xor(mk, off, 64);
      if (ok > mk) mk = ok;
    }
    if (mk != 0ull) {
      unsigned hi = (unsigned)(mk >> 32);
      hi ^= (hi & 0x80000000u) ? 0x80000000u : 0xFFFFFFFFu;
      wv[r] = __uint_as_float(hi);
      wi[r] = 0x7FFFFFFF - (int)(unsigned)(mk & 0xFFFFFFFFu);
    } else {
      wv[r] = 0.f; wi[r] = -1;
    }
    if (kv[0] == mk && mk != 0ull) {
#pragma unroll
      for (int j = 0; j < 7; j++) kv[j] = kv[j + 1];
      kv[7] = 0ull;
    }
  }
  const float mx = wv[0];
  float w8[8]; float den = 0.f;
#pragma unroll
  for (int j = 0; j < 8; j++) {
    w8[j] = (wi[j] >= 0) ? expf(wv[j] - mx) : 0.f;
    den += w8[j];
  }
  const float inv = 1.f / den;
  float a[4] = {0.f, 0.f, 0.f, 0.f};
#pragma unroll
  for (int j = 0; j < 8; j++) {
    if (wi[j] >= 0) {
      const bf16x4 vv = *(const bf16x4*)(QKV + ((long long)b * 1024 + wi[j]) * 768 + 512 + lane * 4);
      const float wj = w8[j] * inv;
#pragma unroll
      for (int e = 0; e < 4; e++) a[e] = fmaf(wj, (float)vv[e], a[e]);
    }
  }
  bf16x4 o4;
#pragma unroll
  for (int e = 0; e < 4; e++) o4[e] = (bf16_t)a[e];
  *(bf16x4*)(O + ((long long)(b * 1024 + n)) * 256 + lane * 4) = o4;
}

// ---------------- prep: weight transposes (f32->bf16), xe, fused biases -----
struct TD { const float* src; bf16_t* dst; int N; int k0; int ld; };  // k0<0: direct copy
struct PrepArgs {
  TD d[16];
  const float* emb; const float* pos; bf16_t* XE;
  const float* msg_b1; const float* msg_b2; const float* upd_w1; const float* upd_b1;
  const float* q_b; const float* k_b; const float* v_b;
  float* BIAS3; float* QKVB;
};

__global__ __launch_bounds__(256) void k_prep(PrepArgs pa) {
  const int y = blockIdx.y, x = blockIdx.x, d = threadIdx.x;
  if (y < 16) {
    TD t = pa.d[y];
    if (x >= t.N) return;
    if (t.k0 < 0) t.dst[(long long)x * 256 + d] = (bf16_t)t.src[(long long)x * t.ld + d];
    else          t.dst[(long long)x * 256 + d] = (bf16_t)t.src[(long long)(t.k0 + d) * t.ld + x];
  } else if (y == 16) {
    const int p = x >> 8, v = x & 255;
    pa.XE[(long long)x * 256 + d] = (bf16_t)(pa.emb[v * 256 + d] + pa.pos[p * 256 + d]);
  } else {
    if      (x == 0) pa.BIAS3[d] = pa.msg_b1[d];
    else if (x == 1) pa.BIAS3[256 + d] = 0.f;
    else if (x == 2) {
      float acc = pa.upd_b1[d];
      for (int k = 0; k < 256; k++) acc += pa.msg_b2[k] * pa.upd_w1[(long long)(256 + k) * 256 + d];
      pa.BIAS3[512 + d] = acc;
    }
    else if (x == 3) pa.QKVB[d] = pa.q_b[d];
    else if (x == 4) pa.QKVB[256 + d] = pa.k_b[d];
    else if (x == 5) pa.QKVB[512 + d] = pa.v_b[d];
  }
}

// ---------------- GRU gate t=0 (bf16 gi table, 4 seqs / 256-thr block) ------
__global__ __launch_bounds__(256)
void k_gru_gate(const int* __restrict__ x, const bf16_t* __restrict__ gitab,
                const float* __restrict__ bhh,
                bf16_t* __restrict__ H, bf16_t* __restrict__ LOC)
{
  const int s = blockIdx.x * 4 + (threadIdx.x >> 6);
  const int lane = threadIdx.x & 63, d0 = lane * 4;
  const int v = x[s * 4];
  const bf16_t* gi = gitab + (long long)v * 768;
  const bf16x4 g_r = *(const bf16x4*)(gi + d0);
  const bf16x4 g_z = *(const bf16x4*)(gi + 256 + d0);
  const bf16x4 g_n = *(const bf16x4*)(gi + 512 + d0);
  bf16x4 ho;
#pragma unroll
  for (int e = 0; e < 4; e++) {
    const float r = sigm((float)g_r[e] + bhh[d0 + e]);
    const float zz = sigm((float)g_z[e] + bhh[256 + d0 + e]);
    const float nn = tanhf((float)g_n[e] + r * (float)bhh[512 + d0 + e]);
    ho[e] = (bf16_t)((1.f - zz) * nn);
  }
  *(bf16x4*)(H + (long long)s * 256 + d0) = ho;
  *(bf16x4*)(LOC + ((long long)s * 4) * 256 + d0) = ho;
}

// ---------------- LN (generic, 4 rows / 256-thr block) ----------------------
__global__ __launch_bounds__(256)
void k_ln(const bf16_t* __restrict__ X, const bf16_t* __restrict__ ADD, int addmode,
          bf16_t* __restrict__ OUT, const float* __restrict__ g,
          const float* __restrict__ b)
{
  const long long r = (long long)blockIdx.x * 4 + (threadIdx.x >> 6);
  const int d0 = (threadIdx.x & 63) * 4;
  const bf16x4 xv = *(const bf16x4*)(X + r * 256 + d0);
  float xf[4];
#pragma unroll
  for (int e = 0; e < 4; e++) xf[e] = (float)xv[e];
  if (addmode == 1) {
    const bf16x4 av = *(const bf16x4*)(ADD + r * 256 + d0);
#pragma unroll
    for (int e = 0; e < 4; e++) xf[e] += (float)av[e];
  } else if (addmode == 2) {
    const bf16x4 av = *(const bf16x4*)(ADD + (r >> 2) * 256 + d0);
#pragma unroll
    for (int e = 0; e < 4; e++) xf[e] += (float)av[e];
  }
  const float mean = wave_sum(xf[0] + xf[1] + xf[2] + xf[3]) * (1.f / 256.f);
  float q = 0.f;
#pragma unroll
  for (int e = 0; e < 4; e++) { const float dx = xf[e] - mean; q += dx * dx; }
  const float rstd = rsqrtf(wave_sum(q) * (1.f / 256.f) + 1e-5f);
  const float4 gv = *(const float4*)(g + d0);
  const float4 bv = *(const float4*)(b + d0);
  const float gg[4] = {gv.x, gv.y, gv.z, gv.w};
  const float bb[4] = {bv.x, bv.y, bv.z, bv.w};
  bf16x4 ov;
#pragma unroll
  for (int e = 0; e < 4; e++) ov[e] = (bf16_t)((xf[e] - mean) * rstd * gg[e] + bb[e]);
  *(bf16x4*)(OUT + r * 256 + d0) = ov;
}

// ---------------- fused patch-LN + mean (4 patches / 256-thr block) ---------
__global__ __launch_bounds__(256)
void k_lnp4(bf16_t* __restrict__ LOC, bf16_t* __restrict__ SUMB,
            const float* __restrict__ g, const float* __restrict__ b)
{
  const long long s = (long long)blockIdx.x * 4 + (threadIdx.x >> 6);
  const int d0 = (threadIdx.x & 63) * 4;
  const float4 gv = *(const float4*)(g + d0);
  const float4 bv = *(const float4*)(b + d0);
  const float gg[4] = {gv.x, gv.y, gv.z, gv.w};
  const float bb[4] = {bv.x, bv.y, bv.z, bv.w};
  float accd[4] = {0.f, 0.f, 0.f, 0.f};
#pragma unroll
  for (int t = 0; t < 4; t++) {
    bf16_t* row = LOC + (s * 4 + t) * 256 + d0;
    const bf16x4 xv = *(const bf16x4*)row;
    float xf[4];
#pragma unroll
    for (int e = 0; e < 4; e++) xf[e] = (float)xv[e];
    const float mean = wave_sum(xf[0] + xf[1] + xf[2] + xf[3]) * (1.f / 256.f);
    float q = 0.f;
#pragma unroll
    for (int e = 0; e < 4; e++) { const float dx = xf[e] - mean; q += dx * dx; }
    const float rstd = rsqrtf(wave_sum(q) * (1.f / 256.f) + 1e-5f);
    bf16x4 ov;
#pragma unroll
    for (int e = 0; e < 4; e++) {
      const float y = (xf[e] - mean) * rstd * gg[e] + bb[e];
      ov[e] = (bf16_t)y;
      accd[e] += y;
    }
    *(bf16x4*)row = ov;
  }
  bf16x4 sv;
#pragma unroll
  for (int e = 0; e < 4; e++) sv[e] = (bf16_t)(accd[e] * 0.25f);
  *(bf16x4*)(SUMB + s * 256 + d0) = sv;
}

// ---------------- gelu-mix over window (A3 stride 512) ----------------------
__global__ __launch_bounds__(256)
void k_gelumix(const bf16_t* __restrict__ A3, bf16_t* __restrict__ G)
{
  const long long s = (long long)blockIdx.x * 4 + (threadIdx.x >> 6);
  const int n = (int)(s & 1023);
  const int d0 = (threadIdx.x & 63) * 4;
  const bf16x4 av = *(const bf16x4*)(A3 + s * 512 + d0);
  float a[4];
#pragma unroll
  for (int e = 0; e < 4; e++) a[e] = (float)av[e];
  float acc[4] = {0.f, 0.f, 0.f, 0.f};
  const bf16_t* bbase = A3 + s * 512 + 256 + d0;
#pragma unroll
  for (int w = 0; w <= 4; w++) {
    if (n >= w) {
      const bf16x4 bn = *(const bf16x4*)(bbase - (long long)w * 512);
#pragma unroll
      for (int e = 0; e < 4; e++) acc[e] += gelu_exact(a[e] + (float)bn[e]);
    } else {
#pragma unroll
      for (int e = 0; e < 4; e++) acc[e] += gelu_exact(a[e]);
    }
  }
  bf16x4 ov;
#pragma unroll
  for (int e = 0; e < 4; e++) ov[e] = (bf16_t)(acc[e] * 0.2f);
  *(bf16x4*)(G + s * 256 + d0) = ov;
}

// ---------------- halting ----------------------------------------------------
__global__ __launch_bounds__(64)
void k_halt1(const bf16_t* __restrict__ Hm, float* __restrict__ PS) {
  const int c = blockIdx.x, b = blockIdx.y, d0 = threadIdx.x * 4;
  float acc[4] = {0.f, 0.f, 0.f, 0.f};
  const bf16_t* base = Hm + ((long long)b * 1024 + c * 32) * 256 + d0;
#pragma unroll 4
  for (int n = 0; n < 32; n++) {
    const bf16x4 hv = *(const bf16x4*)(base + (long long)n * 256);
#pragma unroll
    for (int e = 0; e < 4; e++) acc[e] += (float)hv[e];
  }
  float4 o4; o4.x = acc[0]; o4.y = acc[1]; o4.z = acc[2]; o4.w = acc[3];
  *(float4*)(PS + ((long long)b * 32 + c) * 256 + d0) = o4;
}

// halt2 + kl fused: 1024 threads, 64-thread group per batch b
__global__ __launch_bounds__(1024)
void k_halt2kl(const float* __restrict__ PS, const float* __restrict__ hw,
               const float* __restrict__ hb, float* __restrict__ HP,
               float* __restrict__ out) {
  __shared__ float sh[16];
  const int b = threadIdx.x >> 6, lane = threadIdx.x & 63, d0 = lane * 4;
  float acc[4] = {0.f, 0.f, 0.f, 0.f};
  for (int c = 0; c < 32; c++) {
    const float4 p4 = *(const float4*)(PS + ((long long)b * 32 + c) * 256 + d0);
    acc[0] += p4.x; acc[1] += p4.y; acc[2] += p4.z; acc[3] += p4.w;
  }
  const float4 w4 = *(const float4*)(hw + d0);
  float val = (acc[0] * w4.x + acc[1] * w4.y + acc[2] * w4.z + acc[3] * w4.w) * (1.f / 1024.f);
  val = wave_sum(val);
  if (lane == 0) {
    const float hp = sigm(val + hb[0]);
    HP[b] = hp;
    sh[b] = hp;
  }
  __syncthreads();
  if (threadIdx.x == 0) {
    float s = 0.f;
    for (int bb = 0; bb < 16; bb++) s += sh[bb];
    const float hpm = s * (1.f / 16.f);
    const float l8 = logf(1e-8f);
    const float p0 = 0.2f, p1 = 0.16f, p2 = 0.128f, p3 = 0.1024f;
    const float kl = p0 * (logf(p0) - l8)
                   + p1 * (logf(p1) - l8)
                   + p2 * (logf(p2) - logf(hpm + 1e-8f))
                   + p3 * (logf(p3) - logf(1.f + 1e-8f));
    out[0] = kl * 0.25f;
  }
}

// out_mp init: O = hp[b]*h  (4 rows / 256-thr block)
__global__ __launch_bounds__(256)
void k_outmp(const bf16_t* __restrict__ Hm, const float* __restrict__ HP,
             bf16_t* __restrict__ O) {
  const long long s = (long long)blockIdx.x * 4 + (threadIdx.x >> 6);
  const int d0 = (threadIdx.x & 63) * 4;
  const int b = (int)(s >> 10);
  const float hp = HP[b];
  const bf16x4 hv = *(const bf16x4*)(Hm + s * 256 + d0);
  bf16x4 ov;
#pragma unroll
  for (int e = 0; e < 4; e++) ov[e] = (bf16_t)(hp * (float)hv[e]);
  *(bf16x4*)(O + s * 256 + d0) = ov;
}

// ---------------------------------------------------------------------------
extern "C" void kernel_launch(void* const* d_in, const int* in_sizes, int n_in,
                              void* d_out, int out_size, void* d_ws, size_t ws_size,
                              hipStream_t stream) {
  (void)in_sizes; (void)n_in; (void)ws_size;
  const int*   x      = (const int*)d_in[0];
  const float* emb    = (const float*)d_in[1];
  const float* pos    = (const float*)d_in[2];
  const float* wih    = (const float*)d_in[3];
  const float* whh    = (const float*)d_in[4];
  const float* bih    = (const float*)d_in[5];
  const float* bhh    = (const float*)d_in[6];
  const float* lnp_g  = (const float*)d_in[7];
  const float* lnp_b  = (const float*)d_in[8];
  const float* sum_w  = (const float*)d_in[9];
  const float* sum_b  = (const float*)d_in[10];
  const float* msg_w1 = (const float*)d_in[11];
  const float* msg_b1 = (const float*)d_in[12];
  const float* msg_w2 = (const float*)d_in[13];
  const float* msg_b2 = (const float*)d_in[14];
  const float* upd_w1 = (const float*)d_in[15];
  const float* upd_b1 = (const float*)d_in[16];
  const float* upd_w2 = (const float*)d_in[17];
  const float* upd_b2 = (const float*)d_in[18];
  const float* halt_w = (const float*)d_in[19];
  const float* halt_b = (const float*)d_in[20];
  const float* lnm_g  = (const float*)d_in[21];
  const float* lnm_b  = (const float*)d_in[22];
  const float* q_b    = (const float*)d_in[24];
  const float* k_b    = (const float*)d_in[26];
  const float* v_b    = (const float*)d_in[28];
  const float* o_b    = (const float*)d_in[30];
  const float* bc_b   = (const float*)d_in[32];
  const float* lnf_g  = (const float*)d_in[33];
  const float* lnf_b  = (const float*)d_in[34];

  char* base = (char*)d_ws;
  size_t off = 0;
  auto alloc = [&](size_t bytes) -> void* {
    void* p = (void*)(base + off);
    off += (bytes + 255) & ~(size_t)255;
    return p;
  };
  const size_t SL2 = 16384ull * 256 * 2;   // bf16 activation slab (8 MiB)
  bf16_t* WIHT  = (bf16_t*)alloc(768 * 256 * 2);
  bf16_t* WHHT  = (bf16_t*)alloc(768 * 256 * 2);
  bf16_t* SUMT  = (bf16_t*)alloc(256 * 256 * 2);
  bf16_t* MW    = (bf16_t*)alloc(512 * 256 * 2);   // [msgW1self; msgW1neigh]
  bf16_t* UW1HT = (bf16_t*)alloc(256 * 256 * 2);   // upd_w1 hidden part (Bt form)
  bf16_t* W2T   = (bf16_t*)alloc(256 * 256 * 2);
  bf16_t* W2NT  = (bf16_t*)alloc(256 * 256 * 2);   // msg_w2 direct (row-major)
  bf16_t* UW1MT = (bf16_t*)alloc(256 * 256 * 2);
  bf16_t* UW2T  = (bf16_t*)alloc(256 * 256 * 2);
  bf16_t* WCB   = (bf16_t*)alloc(256 * 256 * 2);   // (msg_w2 @ uw1m) in Bt form
  bf16_t* QKVW  = (bf16_t*)alloc(768 * 256 * 2);
  bf16_t* OT    = (bf16_t*)alloc(256 * 256 * 2);
  bf16_t* BCT   = (bf16_t*)alloc(256 * 256 * 2);
  bf16_t* HEADT = (bf16_t*)alloc(256 * 256 * 2);
  float*  BIAS3 = (float*)alloc(768 * 4);
  float*  QKVB  = (float*)alloc(768 * 4);
  bf16_t* XE    = (bf16_t*)alloc(1024ull * 256 * 2);
  bf16_t* GITAB = (bf16_t*)alloc(1024ull * 768 * 2);
  bf16_t* LOCb  = (bf16_t*)alloc(65536ull * 256 * 2);        // 32 MiB

  // --- 64 MiB overlay: GRU {H2,H} / phase-B {SUMB} / MP {A3} / SCORES ------
  char*   SCR   = (char*)alloc(16ull * 1024 * 1024 * 4);     // 64 MiB
  bf16_t* SCORES = (bf16_t*)SCR;                             // 32 MiB (retrieval)
  bf16_t* H2    = (bf16_t*)SCR;                              //  8 MiB (GRU ping)
  bf16_t* H     = (bf16_t*)(SCR + 25165824);                 //  8 MiB (GRU pong)
  bf16_t* SUMB  = (bf16_t*)(SCR + 33554432);                 //  8 MiB (phase B)
  bf16_t* A3    = (bf16_t*)(SCR + 41943040);                 // 16 MiB (MP rounds)

  bf16_t* HMP   = (bf16_t*)alloc(SL2);
  bf16_t* G     = (bf16_t*)alloc(SL2);
  bf16_t* BROAD = (bf16_t*)alloc(SL2);
  bf16_t* UB    = (bf16_t*)alloc(SL2);   // later ATT
  bf16_t* U2B   = (bf16_t*)alloc(SL2);   // COMB
  bf16_t* OUTMP = (bf16_t*)alloc(SL2);
  bf16_t* QKV   = (bf16_t*)alloc(16384ull * 768 * 2);        // 24 MiB
  float*  PS    = (float*)alloc(512ull * 256 * 4);
  float*  HP    = (float*)alloc(64);
  bf16_t* ATT   = UB;
  bf16_t* COMB  = U2B;
  float*  out   = (float*)d_out;
  float*  klout = out + (out_size - 1);

  // 1) prep: transposes + xe + fused biases
  PrepArgs pa;
  pa.d[0]  = { wih,                    WIHT,            768, 0,   768 };
  pa.d[1]  = { whh,                    WHHT,            768, 0,   768 };
  pa.d[2]  = { sum_w,                  SUMT,            256, 0,   256 };
  pa.d[3]  = { msg_w1,                 MW,              256, 0,   256 };
  pa.d[4]  = { msg_w1,                 MW + 256 * 256,  256, 256, 256 };
  pa.d[5]  = { upd_w1,                 UW1HT,           256, 0,   256 };
  pa.d[6]  = { msg_w2,                 W2T,             256, 0,   256 };
  pa.d[7]  = { upd_w1,                 UW1MT,           256, 256, 256 };
  pa.d[8]  = { upd_w2,                 UW2T,            256, 0,   256 };
  pa.d[9]  = { (const float*)d_in[23], QKVW,            256, 0,   256 };
  pa.d[10] = { (const float*)d_in[25], QKVW + 256*256,  256, 0,   256 };
  pa.d[11] = { (const float*)d_in[27], QKVW + 512*256,  256, 0,   256 };
  pa.d[12] = { (const float*)d_in[29], OT,              256, 0,   256 };
  pa.d[13] = { (const float*)d_in[31], BCT,             256, 0,   256 };
  pa.d[14] = { (const float*)d_in[35], HEADT,           256, 0,   256 };
  pa.d[15] = { msg_w2,                 W2NT,            256, -1,  256 };
  pa.emb = emb; pa.pos = pos; pa.XE = XE;
  pa.msg_b1 = msg_b1; pa.msg_b2 = msg_b2; pa.upd_w1 = upd_w1; pa.upd_b1 = upd_b1;
  pa.q_b = q_b; pa.k_b = k_b; pa.v_b = v_b;
  pa.BIAS3 = BIAS3; pa.QKVB = QKVB;
  k_prep<<<dim3(1024, 18), 256, 0, stream>>>(pa);

  // 1b) WCB[j][i] = sum_k uw1m[k][j] * msg_w2[i][k]  (Bt form of msg_w2@uw1m)
  gemm64<0><<<dim3(4, 4), 256, 0, stream>>>(
      UW1MT, W2NT, WCB, nullptr, nullptr, 256, 256, 256, 0);

  // 2) GRU input table (bf16): gi = (emb+pos) @ wih + bih
  gemm64<GF_BIAS><<<dim3(16, 12), 256, 0, stream>>>(
      XE, WIHT, GITAB, bih, nullptr, 256, 256, 768, 0);

  // 3) GRU: t=0 gate-only; t=1..3 fused GEMM+gate with H ping-pong
  k_gru_gate<<<4096, 256, 0, stream>>>(x, GITAB, bhh, H, LOCb);
  k_gru_fused<<<dim3(256, 2), 256, 0, stream>>>(x, GITAB, WHHT, bhh, H, H2, LOCb, 1);
  k_gru_fused<<<dim3(256, 2), 256, 0, stream>>>(x, GITAB, WHHT, bhh, H2, H, LOCb, 2);
  k_gru_fused<<<dim3(256, 2), 256, 0, stream>>>(x, GITAB, WHHT, bhh, H, H2, LOCb, 3);

  // 4) local = LN(gout) in place + patch means; summaries GEMM
  k_lnp4<<<4096, 256, 0, stream>>>(LOCb, SUMB, lnp_g, lnp_b);
  gemm64<GF_BIAS><<<dim3(256, 4), 256, 0, stream>>>(
      SUMB, SUMT, HMP, sum_b, nullptr, 256, 256, 256, 0);

  // 5) message-passing rounds (WC fusion + K512 dual-A UB GEMM + GEMM-LN)
  for (int step = 0; step < 4; step++) {
    gemm_bt<GF_BIAS><<<dim3(128, 4), 256, 0, stream>>>(
        HMP, MW, A3, BIAS3, nullptr, 256, 256, 512, 0);
    k_gelumix<<<4096, 256, 0, stream>>>(A3, G);
    gemm64_k512<<<dim3(256, 4), 256, 0, stream>>>(
        G, HMP, WCB, UW1HT, UB, BIAS3 + 512);
    if (step == 3) {
      gemm_ln<1><<<256, 256, 0, stream>>>(
          UB, UW2T, HMP, upd_b2, lnm_g, lnm_b, OUTMP, HP);
    } else {
      gemm_ln<0><<<256, 256, 0, stream>>>(
          UB, UW2T, HMP, upd_b2, lnm_g, lnm_b, nullptr, nullptr);
      if (step == 2) {
        k_halt1<<<dim3(32, 16), 64, 0, stream>>>(HMP, PS);
        k_halt2kl<<<1, 1024, 0, stream>>>(PS, halt_w, halt_b, HP, klout);
        k_outmp<<<4096, 256, 0, stream>>>(HMP, HP, OUTMP);
      }
    }
  }

  // 6) retrieval: QKV; causal scores GEMM (bf16 -> SCR); u64 top-8 scan
  gemm_bt<GF_BIAS><<<dim3(128, 6), 256, 0, stream>>>(
      OUTMP, QKVW, QKV, QKVB, nullptr, 256, 256, 768, 0);
  gemm_sc<<<dim3(8, 8, 16), 256, 0, stream>>>(QKV, QKV + 256, SCORES);
  k_topk<<<dim3(256, 16), 256, 0, stream>>>(SCORES, QKV, ATT);
  gemm64<GF_BIAS | GF_RES><<<dim3(256, 4), 256, 0, stream>>>(
      ATT, OT, COMB, o_b, OUTMP, 256, 256, 256, 256);
  gemm64<GF_BIAS><<<dim3(256, 4), 256, 0, stream>>>(
      COMB, BCT, BROAD, bc_b, nullptr, 256, 256, 256, 0);

  // 7) final = LN(local + broad) in place; logits = final @ head_w (f32 out)
  k_ln<<<16384, 256, 0, stream>>>(LOCb, BROAD, 2, LOCb, lnf_g, lnf_b);
  gemm_bt<GF_F32OUT><<<dim3(512, 2), 256, 0, stream>>>(
      LOCb, HEADT, out, nullptr, nullptr, 256, 256, 256, 0);
}

// Round 18
// 447.785 us; speedup vs baseline: 1.0134x; 1.0134x over previous
//
#include <hip/hip_runtime.h>
#include <math.h>

// ---------------------------------------------------------------------------
// B=16, T=4096, D=256, V=256, PATCH=4, Np=1024, BN=16384
// All GEMMs: C[M,N] = A[M,256] @ Bt[N,256]^T (+epilogue), bf16 inputs.
// LDS tiles XOR-swizzled (T2). Sparse top-8 attention: bf16 scores GEMM +
// u64-key scan. MP round: K=512 dual-A GEMM + fused GEMM-LN (32-row blocks,
// 2 blocks/CU). GRU: gemm_bt + gate kernel (R16 config, best measured).
// ---------------------------------------------------------------------------

typedef __bf16 bf16_t;
typedef bf16_t bf16x8 __attribute__((ext_vector_type(8)));
typedef bf16_t bf16x4 __attribute__((ext_vector_type(4)));
typedef float f32x4 __attribute__((ext_vector_type(4)));

#define GF_BIAS 1
#define GF_GELU 4
#define GF_RES 8
#define GF_F32OUT 32

__device__ __forceinline__ float gelu_exact(float x) {
  return 0.5f * x * (1.0f + erff(x * 0.7071067811865475f));
}

__device__ __forceinline__ float sigm(float x) { return 1.f / (1.f + expf(-x)); }

__device__ __forceinline__ float wave_sum(float v) {
#pragma unroll
  for (int o = 32; o; o >>= 1) v += __shfl_xor(v, o, 64);
  return v;
}

__device__ __forceinline__ void gload16(const void* g, void* l) {
  __builtin_amdgcn_global_load_lds(
      (const __attribute__((address_space(1))) void*)g,
      (__attribute__((address_space(3))) void*)l, 16, 0, 0);
}

// sortable u64 key: (order-preserving f32 map) << 32 | (0x7FFFFFFF - m)
// larger key == (larger score, then lower index). Key 0 == empty slot.
__device__ __forceinline__ unsigned long long skey(float s, int m) {
  unsigned u = __float_as_uint(s);
  u ^= (u & 0x80000000u) ? 0xFFFFFFFFu : 0x80000000u;
  return ((unsigned long long)u << 32) | (unsigned)(0x7FFFFFFF - m);
}

// ---------------- bf16 MFMA GEMM: 128x128 tile, 4 waves, BK=64, swizzled ----
template<int FLAGS>
__global__ __launch_bounds__(256)
void gemm_bt(const bf16_t* __restrict__ A, const bf16_t* __restrict__ Bt,
             void* __restrict__ Cv, const float* __restrict__ bias,
             const bf16_t* __restrict__ res,
             int lda, int ldb, int ldc, int ldr)
{
  __shared__ __align__(16) bf16_t As[128][64];
  __shared__ __align__(16) bf16_t Bs[128][64];
  const int m0 = blockIdx.x * 128, n0 = blockIdx.y * 128;
  const int tid = threadIdx.x, lane = tid & 63, wave = tid >> 6;
  const int wm = (wave >> 1) << 6, wn = (wave & 1) << 6;
  const int lr = lane & 15, lg = lane >> 4;
  const int cx = lane & 7;

  const int srow = wave * 32 + (lane >> 3);
  const int scol = (((lane & 7) ^ ((lane >> 3) & 7)) * 8);
  const bf16_t* ga = A  + (long long)(m0 + srow) * lda + scol;
  const bf16_t* gb = Bt + (long long)(n0 + srow) * ldb + scol;
  char* lA = (char*)(&As[srow][0]) + (lane & 7) * 16;
  char* lB = (char*)(&Bs[srow][0]) + (lane & 7) * 16;

  f32x4 acc[4][4] = {};

#pragma unroll
  for (int kt = 0; kt < 4; kt++) {
    const int ko = kt * 64;
#pragma unroll
    for (int q = 0; q < 4; q++) {
      gload16(ga + (long long)q * 8 * lda + ko, lA + q * 1024);
      gload16(gb + (long long)q * 8 * ldb + ko, lB + q * 1024);
    }
    __syncthreads();
#pragma unroll
    for (int kk = 0; kk < 2; kk++) {
      const int co = ((kk * 4 + lg) ^ cx) << 4;
      bf16x8 af[4], bfv[4];
#pragma unroll
      for (int i = 0; i < 4; i++)
        af[i]  = *(const bf16x8*)((char*)As + (wm + i * 16 + lr) * 128 + co);
#pragma unroll
      for (int j = 0; j < 4; j++)
        bfv[j] = *(const bf16x8*)((char*)Bs + (wn + j * 16 + lr) * 128 + co);
#pragma unroll
      for (int i = 0; i < 4; i++)
#pragma unroll
        for (int j = 0; j < 4; j++)
          acc[i][j] = __builtin_amdgcn_mfma_f32_16x16x32_bf16(af[i], bfv[j], acc[i][j], 0, 0, 0);
    }
    if (kt < 3) __syncthreads();
  }

#pragma unroll
  for (int i = 0; i < 4; i++) {
#pragma unroll
    for (int j = 0; j < 4; j++) {
      const int col = n0 + wn + j * 16 + lr;
      const float bval = (FLAGS & GF_BIAS) ? bias[col] : 0.f;
#pragma unroll
      for (int e = 0; e < 4; e++) {
        const int row = m0 + wm + i * 16 + lg * 4 + e;
        float v = acc[i][j][e] + bval;
        if (FLAGS & GF_RES) v += (float)res[(long long)row * ldr + col];
        if (FLAGS & GF_GELU) v = gelu_exact(v);
        const long long ci = (long long)row * ldc + col;
        if (FLAGS & GF_F32OUT) ((float*)Cv)[ci] = v;
        else                   ((bf16_t*)Cv)[ci] = (bf16_t)v;
      }
    }
  }
}

// ---------------- causal scores GEMM: z-batched, scaled, masked, bf16 -------
__global__ __launch_bounds__(256)
void gemm_sc(const bf16_t* __restrict__ Qb, const bf16_t* __restrict__ Kb,
             bf16_t* __restrict__ S)
{
  __shared__ __align__(16) bf16_t As[128][64];
  __shared__ __align__(16) bf16_t Bs[128][64];
  const int z = blockIdx.z;
  const int m0 = blockIdx.x * 128, n0 = blockIdx.y * 128;
  if (n0 > m0) return;  // tile fully above diagonal
  const bf16_t* A  = Qb + (long long)z * (1024LL * 768);
  const bf16_t* Bt = Kb + (long long)z * (1024LL * 768);
  bf16_t* C = S + (long long)z * (1024LL * 1024);
  const int tid = threadIdx.x, lane = tid & 63, wave = tid >> 6;
  const int wm = (wave >> 1) << 6, wn = (wave & 1) << 6;
  const int lr = lane & 15, lg = lane >> 4;
  const int cx = lane & 7;

  const int srow = wave * 32 + (lane >> 3);
  const int scol = (((lane & 7) ^ ((lane >> 3) & 7)) * 8);
  const bf16_t* ga = A  + (long long)(m0 + srow) * 768 + scol;
  const bf16_t* gb = Bt + (long long)(n0 + srow) * 768 + scol;
  char* lA = (char*)(&As[srow][0]) + (lane & 7) * 16;
  char* lB = (char*)(&Bs[srow][0]) + (lane & 7) * 16;

  f32x4 acc[4][4] = {};

#pragma unroll
  for (int kt = 0; kt < 4; kt++) {
    const int ko = kt * 64;
#pragma unroll
    for (int q = 0; q < 4; q++) {
      gload16(ga + (long long)q * 8 * 768 + ko, lA + q * 1024);
      gload16(gb + (long long)q * 8 * 768 + ko, lB + q * 1024);
    }
    __syncthreads();
#pragma unroll
    for (int kk = 0; kk < 2; kk++) {
      const int co = ((kk * 4 + lg) ^ cx) << 4;
      bf16x8 af[4], bfv[4];
#pragma unroll
      for (int i = 0; i < 4; i++)
        af[i]  = *(const bf16x8*)((char*)As + (wm + i * 16 + lr) * 128 + co);
#pragma unroll
      for (int j = 0; j < 4; j++)
        bfv[j] = *(const bf16x8*)((char*)Bs + (wn + j * 16 + lr) * 128 + co);
#pragma unroll
      for (int i = 0; i < 4; i++)
#pragma unroll
        for (int j = 0; j < 4; j++)
          acc[i][j] = __builtin_amdgcn_mfma_f32_16x16x32_bf16(af[i], bfv[j], acc[i][j], 0, 0, 0);
    }
    if (kt < 3) __syncthreads();
  }

#pragma unroll
  for (int i = 0; i < 4; i++) {
#pragma unroll
    for (int j = 0; j < 4; j++) {
      const int col = n0 + wn + j * 16 + lr;
#pragma unroll
      for (int e = 0; e < 4; e++) {
        const int row = m0 + wm + i * 16 + lg * 4 + e;
        float v = acc[i][j][e] * 0.0625f;
        if (col > row) v = -__builtin_inff();
        C[(long long)row * 1024 + col] = (bf16_t)v;
      }
    }
  }
}

// ---------------- bf16 MFMA GEMM: 64x64 tile, 4 waves, BK=64, swizzled ------
template<int FLAGS>
__global__ __launch_bounds__(256)
void gemm64(const bf16_t* __restrict__ A, const bf16_t* __restrict__ Bt,
            void* __restrict__ Cv, const float* __restrict__ bias,
            const bf16_t* __restrict__ res,
            int lda, int ldb, int ldc, int ldr)
{
  __shared__ __align__(16) bf16_t As[64][64];
  __shared__ __align__(16) bf16_t Bs[64][64];
  const int m0 = blockIdx.x * 64, n0 = blockIdx.y * 64;
  const int tid = threadIdx.x, lane = tid & 63, wave = tid >> 6;
  const int wm = (wave >> 1) * 32, wn = (wave & 1) * 32;
  const int lr = lane & 15, lg = lane >> 4;
  const int cx = lane & 7;

  const int srow = tid >> 3;
  const int scol = (((tid & 7) ^ (srow & 7)) * 8);
  const bf16_t* ga = A  + (long long)(m0 + srow) * lda + scol;
  const bf16_t* gb = Bt + (long long)(n0 + srow) * ldb + scol;
  char* lA = (char*)As + tid * 16;
  char* lB = (char*)Bs + tid * 16;

  f32x4 acc[2][2] = {};

#pragma unroll
  for (int kt = 0; kt < 4; kt++) {
    const int ko = kt * 64;
    gload16(ga + ko, lA);
    gload16(ga + 32LL * lda + ko, lA + 4096);
    gload16(gb + ko, lB);
    gload16(gb + 32LL * ldb + ko, lB + 4096);
    __syncthreads();
#pragma unroll
    for (int kk = 0; kk < 2; kk++) {
      const int co = ((kk * 4 + lg) ^ cx) << 4;
      bf16x8 af[2], bfv[2];
#pragma unroll
      for (int i = 0; i < 2; i++)
        af[i]  = *(const bf16x8*)((char*)As + (wm + i * 16 + lr) * 128 + co);
#pragma unroll
      for (int j = 0; j < 2; j++)
        bfv[j] = *(const bf16x8*)((char*)Bs + (wn + j * 16 + lr) * 128 + co);
#pragma unroll
      for (int i = 0; i < 2; i++)
#pragma unroll
        for (int j = 0; j < 2; j++)
          acc[i][j] = __builtin_amdgcn_mfma_f32_16x16x32_bf16(af[i], bfv[j], acc[i][j], 0, 0, 0);
    }
    if (kt < 3) __syncthreads();
  }

#pragma unroll
  for (int i = 0; i < 2; i++) {
#pragma unroll
    for (int j = 0; j < 2; j++) {
      const int col = n0 + wn + j * 16 + lr;
      const float bval = (FLAGS & GF_BIAS) ? bias[col] : 0.f;
#pragma unroll
      for (int e = 0; e < 4; e++) {
        const int row = m0 + wm + i * 16 + lg * 4 + e;
        float v = acc[i][j][e] + bval;
        if (FLAGS & GF_RES) v += (float)res[(long long)row * ldr + col];
        if (FLAGS & GF_GELU) v = gelu_exact(v);
        const long long ci = (long long)row * ldc + col;
        if (FLAGS & GF_F32OUT) ((float*)Cv)[ci] = v;
        else                   ((bf16_t*)Cv)[ci] = (bf16_t)v;
      }
    }
  }
}

// ---------------- dual-A K=512 gemm64: C = gelu(A1@Bt1 + A2@Bt2 + bias) -----
__global__ __launch_bounds__(256)
void gemm64_k512(const bf16_t* __restrict__ A1, const bf16_t* __restrict__ A2,
                 const bf16_t* __restrict__ Bt1, const bf16_t* __restrict__ Bt2,
                 bf16_t* __restrict__ C, const float* __restrict__ bias)
{
  __shared__ __align__(16) bf16_t As[64][64];
  __shared__ __align__(16) bf16_t Bs[64][64];
  const int m0 = blockIdx.x * 64, n0 = blockIdx.y * 64;
  const int tid = threadIdx.x, lane = tid & 63, wave = tid >> 6;
  const int wm = (wave >> 1) * 32, wn = (wave & 1) * 32;
  const int lr = lane & 15, lg = lane >> 4;
  const int cx = lane & 7;

  const int srow = tid >> 3;
  const int scol = (((tid & 7) ^ (srow & 7)) * 8);
  char* lA = (char*)As + tid * 16;
  char* lB = (char*)Bs + tid * 16;

  f32x4 acc[2][2] = {};

#pragma unroll
  for (int kt = 0; kt < 8; kt++) {
    const bf16_t* Ap  = (kt < 4) ? A1 : A2;
    const bf16_t* Btp = (kt < 4) ? Bt1 : Bt2;
    const int ko = (kt & 3) * 64;
    const bf16_t* ga = Ap  + (long long)(m0 + srow) * 256 + scol + ko;
    const bf16_t* gb = Btp + (long long)(n0 + srow) * 256 + scol + ko;
    gload16(ga, lA);
    gload16(ga + 32LL * 256, lA + 4096);
    gload16(gb, lB);
    gload16(gb + 32LL * 256, lB + 4096);
    __syncthreads();
#pragma unroll
    for (int kk = 0; kk < 2; kk++) {
      const int co = ((kk * 4 + lg) ^ cx) << 4;
      bf16x8 af[2], bfv[2];
#pragma unroll
      for (int i = 0; i < 2; i++)
        af[i]  = *(const bf16x8*)((char*)As + (wm + i * 16 + lr) * 128 + co);
#pragma unroll
      for (int j = 0; j < 2; j++)
        bfv[j] = *(const bf16x8*)((char*)Bs + (wn + j * 16 + lr) * 128 + co);
#pragma unroll
      for (int i = 0; i < 2; i++)
#pragma unroll
        for (int j = 0; j < 2; j++)
          acc[i][j] = __builtin_amdgcn_mfma_f32_16x16x32_bf16(af[i], bfv[j], acc[i][j], 0, 0, 0);
    }
    if (kt < 7) __syncthreads();
  }

#pragma unroll
  for (int i = 0; i < 2; i++) {
#pragma unroll
    for (int j = 0; j < 2; j++) {
      const int col = n0 + wn + j * 16 + lr;
      const float bval = bias[col];
#pragma unroll
      for (int e = 0; e < 4; e++) {
        const int row = m0 + wm + i * 16 + lg * 4 + e;
        C[(long long)row * 256 + col] = (bf16_t)gelu_exact(acc[i][j][e] + bval);
      }
    }
  }
}

// ---------------- fused GEMM + LayerNorm (32 rows x full N=256) -------------
// MODE 0: C = LN(C + A@Bt + bias)           (in place on C, block-owned rows)
// MODE 1: OUTMP += (1-HP[b]) * LN(C + A@Bt + bias)   (C unchanged/dead)
// 32-row blocks -> 512 blocks (2/CU) for latency hiding.
template<int MODE>
__global__ __launch_bounds__(256)
void gemm_ln(const bf16_t* __restrict__ A, const bf16_t* __restrict__ Bt,
             bf16_t* __restrict__ C, const float* __restrict__ bias,
             const float* __restrict__ g, const float* __restrict__ bvec,
             bf16_t* __restrict__ OUTMP, const float* __restrict__ HP)
{
  __shared__ __align__(16) bf16_t As[32][64];
  __shared__ __align__(16) bf16_t Bs[256][64];
  __shared__ float redsum[4][32];
  __shared__ float redsq[4][32];
  const int m0 = blockIdx.x * 32;
  const int tid = threadIdx.x, lane = tid & 63, w = tid >> 6;
  const int lr = lane & 15, lg = lane >> 4, cx = lane & 7;

  f32x4 acc[2][4] = {};

#pragma unroll
  for (int kt = 0; kt < 4; kt++) {
    const int ko = kt * 64;
    {
      const int r = tid >> 3, c = tid & 7;
      gload16(A + (long long)(m0 + r) * 256 + ko + ((c ^ (r & 7)) * 8), (char*)As + tid * 16);
    }
#pragma unroll
    for (int it = 0; it < 8; it++) {
      const int cid = it * 256 + tid, r = cid >> 3, c = cid & 7;
      gload16(Bt + (long long)r * 256 + ko + ((c ^ (r & 7)) * 8), (char*)Bs + cid * 16);
    }
    __syncthreads();
#pragma unroll
    for (int kk = 0; kk < 2; kk++) {
      const int co = ((kk * 4 + lg) ^ cx) << 4;
      bf16x8 af[2], bfv[4];
#pragma unroll
      for (int i = 0; i < 2; i++)
        af[i]  = *(const bf16x8*)((char*)As + (i * 16 + lr) * 128 + co);
#pragma unroll
      for (int j = 0; j < 4; j++)
        bfv[j] = *(const bf16x8*)((char*)Bs + (w * 64 + j * 16 + lr) * 128 + co);
#pragma unroll
      for (int i = 0; i < 2; i++)
#pragma unroll
        for (int j = 0; j < 4; j++)
          acc[i][j] = __builtin_amdgcn_mfma_f32_16x16x32_bf16(af[i], bfv[j], acc[i][j], 0, 0, 0);
    }
    if (kt < 3) __syncthreads();
  }

  float v[2][4][4];
  float rs[2][4], rq[2][4];
#pragma unroll
  for (int i = 0; i < 2; i++) {
#pragma unroll
    for (int e = 0; e < 4; e++) { rs[i][e] = 0.f; rq[i][e] = 0.f; }
  }
#pragma unroll
  for (int i = 0; i < 2; i++) {
#pragma unroll
    for (int j = 0; j < 4; j++) {
      const int col = w * 64 + j * 16 + lr;
      const float bval = bias[col];
#pragma unroll
      for (int e = 0; e < 4; e++) {
        const long long rg = m0 + i * 16 + lg * 4 + e;
        const float val = acc[i][j][e] + bval + (float)C[rg * 256 + col];
        v[i][j][e] = val;
        rs[i][e] += val;
        rq[i][e] += val * val;
      }
    }
  }
#pragma unroll
  for (int off = 1; off < 16; off <<= 1) {
#pragma unroll
    for (int i = 0; i < 2; i++)
#pragma unroll
      for (int e = 0; e < 4; e++) {
        rs[i][e] += __shfl_xor(rs[i][e], off, 64);
        rq[i][e] += __shfl_xor(rq[i][e], off, 64);
      }
  }
  if (lr == 0) {
#pragma unroll
    for (int i = 0; i < 2; i++)
#pragma unroll
      for (int e = 0; e < 4; e++) {
        redsum[w][i * 16 + lg * 4 + e] = rs[i][e];
        redsq[w][i * 16 + lg * 4 + e]  = rq[i][e];
      }
  }
  __syncthreads();
  float mean[2][4], rstd[2][4];
#pragma unroll
  for (int i = 0; i < 2; i++) {
#pragma unroll
    for (int e = 0; e < 4; e++) {
      const int r = i * 16 + lg * 4 + e;
      const float S = redsum[0][r] + redsum[1][r] + redsum[2][r] + redsum[3][r];
      const float Q = redsq[0][r] + redsq[1][r] + redsq[2][r] + redsq[3][r];
      const float m = S * (1.f / 256.f);
      float var = Q * (1.f / 256.f) - m * m;
      if (var < 0.f) var = 0.f;
      mean[i][e] = m;
      rstd[i][e] = rsqrtf(var + 1e-5f);
    }
  }
#pragma unroll
  for (int i = 0; i < 2; i++) {
#pragma unroll
    for (int j = 0; j < 4; j++) {
      const int col = w * 64 + j * 16 + lr;
      const float gg = g[col], bb = bvec[col];
#pragma unroll
      for (int e = 0; e < 4; e++) {
        const long long rg = m0 + i * 16 + lg * 4 + e;
        const float y = (v[i][j][e] - mean[i][e]) * rstd[i][e] * gg + bb;
        if (MODE == 0) {
          C[rg * 256 + col] = (bf16_t)y;
        } else {
          const float rem = 1.f - HP[(int)(rg >> 10)];
          OUTMP[rg * 256 + col] = (bf16_t)((float)OUTMP[rg * 256 + col] + rem * y);
        }
      }
    }
  }
}

// ---------------- top-8 causal sparse attention (bf16 scores, u64 keys) -----
__global__ __launch_bounds__(256)
void k_topk(const bf16_t* __restrict__ S, const bf16_t* __restrict__ QKV,
            bf16_t* __restrict__ O) {
  const int n = blockIdx.x * 4 + (threadIdx.x >> 6);
  const int b = blockIdx.y;
  const int lane = threadIdx.x & 63;
  const bf16_t* srow = S + ((long long)(b * 1024 + n)) * 1024;
  unsigned long long kv[8] = {0, 0, 0, 0, 0, 0, 0, 0};
  for (int mb = lane * 8; mb <= n; mb += 512) {
    const bf16x8 s8 = *(const bf16x8*)(srow + mb);
#pragma unroll
    for (int jj = 0; jj < 8; jj++) {
      const int m = mb + jj;
      if (m <= n) {
        const unsigned long long k = skey((float)s8[jj], m);
        if (k > kv[7]) {
          kv[7] = k;
#pragma unroll
          for (int j = 7; j > 0; j--) {
            if (kv[j] > kv[j-1]) {
              const unsigned long long t = kv[j]; kv[j] = kv[j-1]; kv[j-1] = t;
            }
          }
        }
      }
    }
  }
  // 8 rounds of wave-wide u64 max; winner lane pops its list head
  float wv[8]; int wi[8];
#pragma unroll
  for (int r = 0; r < 8; r++) {
    unsigned long long mk = kv[0];
#pragma unroll
    for (int off = 32; off; off >>= 1) {
      const unsigned long long ok = __shfl_xor(mk, off, 64);
      if (ok > mk) mk = ok;
    }
    if (mk != 0ull) {
      unsigned hi = (unsigned)(mk >> 32);
      hi ^= (hi & 0x80000000u) ? 0x80000000u : 0xFFFFFFFFu;
      wv[r] = __uint_as_float(hi);
      wi[r] = 0x7FFFFFFF - (int)(unsigned)(mk & 0xFFFFFFFFu);
    } else {
      wv[r] = 0.f; wi[r] = -1;
    }
    if (kv[0] == mk && mk != 0ull) {
#pragma unroll
      for (int j = 0; j < 7; j++) kv[j] = kv[j + 1];
      kv[7] = 0ull;
    }
  }
  const float mx = wv[0];
  float w8[8]; float den = 0.f;
#pragma unroll
  for (int j = 0; j < 8; j++) {
    w8[j] = (wi[j] >= 0) ? expf(wv[j] - mx) : 0.f;
    den += w8[j];
  }
  const float inv = 1.f / den;
  float a[4] = {0.f, 0.f, 0.f, 0.f};
#pragma unroll
  for (int j = 0; j < 8; j++) {
    if (wi[j] >= 0) {
      const bf16x4 vv = *(const bf16x4*)(QKV + ((long long)b * 1024 + wi[j]) * 768 + 512 + lane * 4);
      const float wj = w8[j] * inv;
#pragma unroll
      for (int e = 0; e < 4; e++) a[e] = fmaf(wj, (float)vv[e], a[e]);
    }
  }
  bf16x4 o4;
#pragma unroll
  for (int e = 0; e < 4; e++) o4[e] = (bf16_t)a[e];
  *(bf16x4*)(O + ((long long)(b * 1024 + n)) * 256 + lane * 4) = o4;
}

// ---------------- prep: weight transposes (f32->bf16), xe, fused biases -----
struct TD { const float* src; bf16_t* dst; int N; int k0; int ld; };  // k0<0: direct copy
struct PrepArgs {
  TD d[16];
  const float* emb; const float* pos; bf16_t* XE;
  const float* msg_b1; const float* msg_b2; const float* upd_w1; const float* upd_b1;
  const float* q_b; const float* k_b; const float* v_b;
  float* BIAS3; float* QKVB;
};

__global__ __launch_bounds__(256) void k_prep(PrepArgs pa) {
  const int y = blockIdx.y, x = blockIdx.x, d = threadIdx.x;
  if (y < 16) {
    TD t = pa.d[y];
    if (x >= t.N) return;
    if (t.k0 < 0) t.dst[(long long)x * 256 + d] = (bf16_t)t.src[(long long)x * t.ld + d];
    else          t.dst[(long long)x * 256 + d] = (bf16_t)t.src[(long long)(t.k0 + d) * t.ld + x];
  } else if (y == 16) {
    const int p = x >> 8, v = x & 255;
    pa.XE[(long long)x * 256 + d] = (bf16_t)(pa.emb[v * 256 + d] + pa.pos[p * 256 + d]);
  } else {
    if      (x == 0) pa.BIAS3[d] = pa.msg_b1[d];
    else if (x == 1) pa.BIAS3[256 + d] = 0.f;
    else if (x == 2) {
      float acc = pa.upd_b1[d];
      for (int k = 0; k < 256; k++) acc += pa.msg_b2[k] * pa.upd_w1[(long long)(256 + k) * 256 + d];
      pa.BIAS3[512 + d] = acc;
    }
    else if (x == 3) pa.QKVB[d] = pa.q_b[d];
    else if (x == 4) pa.QKVB[256 + d] = pa.k_b[d];
    else if (x == 5) pa.QKVB[512 + d] = pa.v_b[d];
  }
}

// ---------------- GRU gate (bf16 gi table, 4 seqs / 256-thr block) ----------
__global__ __launch_bounds__(256)
void k_gru_gate(const int* __restrict__ x, const bf16_t* __restrict__ gitab,
                const bf16_t* __restrict__ GH, const float* __restrict__ bhh,
                bf16_t* __restrict__ H, bf16_t* __restrict__ LOC, int t)
{
  const int s = blockIdx.x * 4 + (threadIdx.x >> 6);
  const int lane = threadIdx.x & 63, d0 = lane * 4;
  const int v = x[s * 4 + t];
  const bf16_t* gi = gitab + (long long)(t * 256 + v) * 768;
  const bf16x4 g_r = *(const bf16x4*)(gi + d0);
  const bf16x4 g_z = *(const bf16x4*)(gi + 256 + d0);
  const bf16x4 g_n = *(const bf16x4*)(gi + 512 + d0);
  float hr[4], hz[4], hn[4], hp[4];
  if (t == 0) {
#pragma unroll
    for (int e = 0; e < 4; e++) {
      hr[e] = bhh[d0 + e]; hz[e] = bhh[256 + d0 + e]; hn[e] = bhh[512 + d0 + e];
      hp[e] = 0.f;
    }
  } else {
    const bf16_t* gh = GH + (long long)s * 768;
    const bf16x4 a = *(const bf16x4*)(gh + d0);
    const bf16x4 b4 = *(const bf16x4*)(gh + 256 + d0);
    const bf16x4 c4 = *(const bf16x4*)(gh + 512 + d0);
    const bf16x4 hv = *(const bf16x4*)(H + (long long)s * 256 + d0);
#pragma unroll
    for (int e = 0; e < 4; e++) { hr[e] = a[e]; hz[e] = b4[e]; hn[e] = c4[e]; hp[e] = hv[e]; }
  }
  bf16x4 ho;
#pragma unroll
  for (int e = 0; e < 4; e++) {
    const float r = sigm((float)g_r[e] + hr[e]);
    const float zz = sigm((float)g_z[e] + hz[e]);
    const float nn = tanhf((float)g_n[e] + r * hn[e]);
    ho[e] = (bf16_t)((1.f - zz) * nn + zz * hp[e]);
  }
  *(bf16x4*)(H + (long long)s * 256 + d0) = ho;
  *(bf16x4*)(LOC + ((long long)s * 4 + t) * 256 + d0) = ho;
}

// ---------------- LN (generic, 4 rows / 256-thr block) ----------------------
__global__ __launch_bounds__(256)
void k_ln(const bf16_t* __restrict__ X, const bf16_t* __restrict__ ADD, int addmode,
          bf16_t* __restrict__ OUT, const float* __restrict__ g,
          const float* __restrict__ b)
{
  const long long r = (long long)blockIdx.x * 4 + (threadIdx.x >> 6);
  const int d0 = (threadIdx.x & 63) * 4;
  const bf16x4 xv = *(const bf16x4*)(X + r * 256 + d0);
  float xf[4];
#pragma unroll
  for (int e = 0; e < 4; e++) xf[e] = (float)xv[e];
  if (addmode == 1) {
    const bf16x4 av = *(const bf16x4*)(ADD + r * 256 + d0);
#pragma unroll
    for (int e = 0; e < 4; e++) xf[e] += (float)av[e];
  } else if (addmode == 2) {
    const bf16x4 av = *(const bf16x4*)(ADD + (r >> 2) * 256 + d0);
#pragma unroll
    for (int e = 0; e < 4; e++) xf[e] += (float)av[e];
  }
  const float mean = wave_sum(xf[0] + xf[1] + xf[2] + xf[3]) * (1.f / 256.f);
  float q = 0.f;
#pragma unroll
  for (int e = 0; e < 4; e++) { const float dx = xf[e] - mean; q += dx * dx; }
  const float rstd = rsqrtf(wave_sum(q) * (1.f / 256.f) + 1e-5f);
  const float4 gv = *(const float4*)(g + d0);
  const float4 bv = *(const float4*)(b + d0);
  const float gg[4] = {gv.x, gv.y, gv.z, gv.w};
  const float bb[4] = {bv.x, bv.y, bv.z, bv.w};
  bf16x4 ov;
#pragma unroll
  for (int e = 0; e < 4; e++) ov[e] = (bf16_t)((xf[e] - mean) * rstd * gg[e] + bb[e]);
  *(bf16x4*)(OUT + r * 256 + d0) = ov;
}

// ---------------- fused patch-LN + mean (4 patches / 256-thr block) ---------
__global__ __launch_bounds__(256)
void k_lnp4(bf16_t* __restrict__ LOC, bf16_t* __restrict__ SUMB,
            const float* __restrict__ g, const float* __restrict__ b)
{
  const long long s = (long long)blockIdx.x * 4 + (threadIdx.x >> 6);
  const int d0 = (threadIdx.x & 63) * 4;
  const float4 gv = *(const float4*)(g + d0);
  const float4 bv = *(const float4*)(b + d0);
  const float gg[4] = {gv.x, gv.y, gv.z, gv.w};
  const float bb[4] = {bv.x, bv.y, bv.z, bv.w};
  float accd[4] = {0.f, 0.f, 0.f, 0.f};
#pragma unroll
  for (int t = 0; t < 4; t++) {
    bf16_t* row = LOC + (s * 4 + t) * 256 + d0;
    const bf16x4 xv = *(const bf16x4*)row;
    float xf[4];
#pragma unroll
    for (int e = 0; e < 4; e++) xf[e] = (float)xv[e];
    const float mean = wave_sum(xf[0] + xf[1] + xf[2] + xf[3]) * (1.f / 256.f);
    float q = 0.f;
#pragma unroll
    for (int e = 0; e < 4; e++) { const float dx = xf[e] - mean; q += dx * dx; }
    const float rstd = rsqrtf(wave_sum(q) * (1.f / 256.f) + 1e-5f);
    bf16x4 ov;
#pragma unroll
    for (int e = 0; e < 4; e++) {
      const float y = (xf[e] - mean) * rstd * gg[e] + bb[e];
      ov[e] = (bf16_t)y;
      accd[e] += y;
    }
    *(bf16x4*)row = ov;
  }
  bf16x4 sv;
#pragma unroll
  for (int e = 0; e < 4; e++) sv[e] = (bf16_t)(accd[e] * 0.25f);
  *(bf16x4*)(SUMB + s * 256 + d0) = sv;
}

// ---------------- gelu-mix over window (A3 stride 512) ----------------------
__global__ __launch_bounds__(256)
void k_gelumix(const bf16_t* __restrict__ A3, bf16_t* __restrict__ G)
{
  const long long s = (long long)blockIdx.x * 4 + (threadIdx.x >> 6);
  const int n = (int)(s & 1023);
  const int d0 = (threadIdx.x & 63) * 4;
  const bf16x4 av = *(const bf16x4*)(A3 + s * 512 + d0);
  float a[4];
#pragma unroll
  for (int e = 0; e < 4; e++) a[e] = (float)av[e];
  float acc[4] = {0.f, 0.f, 0.f, 0.f};
  const bf16_t* bbase = A3 + s * 512 + 256 + d0;
#pragma unroll
  for (int w = 0; w <= 4; w++) {
    if (n >= w) {
      const bf16x4 bn = *(const bf16x4*)(bbase - (long long)w * 512);
#pragma unroll
      for (int e = 0; e < 4; e++) acc[e] += gelu_exact(a[e] + (float)bn[e]);
    } else {
#pragma unroll
      for (int e = 0; e < 4; e++) acc[e] += gelu_exact(a[e]);
    }
  }
  bf16x4 ov;
#pragma unroll
  for (int e = 0; e < 4; e++) ov[e] = (bf16_t)(acc[e] * 0.2f);
  *(bf16x4*)(G + s * 256 + d0) = ov;
}

// ---------------- halting ----------------------------------------------------
__global__ __launch_bounds__(64)
void k_halt1(const bf16_t* __restrict__ Hm, float* __restrict__ PS) {
  const int c = blockIdx.x, b = blockIdx.y, d0 = threadIdx.x * 4;
  float acc[4] = {0.f, 0.f, 0.f, 0.f};
  const bf16_t* base = Hm + ((long long)b * 1024 + c * 32) * 256 + d0;
#pragma unroll 4
  for (int n = 0; n < 32; n++) {
    const bf16x4 hv = *(const bf16x4*)(base + (long long)n * 256);
#pragma unroll
    for (int e = 0; e < 4; e++) acc[e] += (float)hv[e];
  }
  float4 o4; o4.x = acc[0]; o4.y = acc[1]; o4.z = acc[2]; o4.w = acc[3];
  *(float4*)(PS + ((long long)b * 32 + c) * 256 + d0) = o4;
}

// halt2 + kl fused: 1024 threads, 64-thread group per batch b
__global__ __launch_bounds__(1024)
void k_halt2kl(const float* __restrict__ PS, const float* __restrict__ hw,
               const float* __restrict__ hb, float* __restrict__ HP,
               float* __restrict__ out) {
  __shared__ float sh[16];
  const int b = threadIdx.x >> 6, lane = threadIdx.x & 63, d0 = lane * 4;
  float acc[4] = {0.f, 0.f, 0.f, 0.f};
  for (int c = 0; c < 32; c++) {
    const float4 p4 = *(const float4*)(PS + ((long long)b * 32 + c) * 256 + d0);
    acc[0] += p4.x; acc[1] += p4.y; acc[2] += p4.z; acc[3] += p4.w;
  }
  const float4 w4 = *(const float4*)(hw + d0);
  float val = (acc[0] * w4.x + acc[1] * w4.y + acc[2] * w4.z + acc[3] * w4.w) * (1.f / 1024.f);
  val = wave_sum(val);
  if (lane == 0) {
    const float hp = sigm(val + hb[0]);
    HP[b] = hp;
    sh[b] = hp;
  }
  __syncthreads();
  if (threadIdx.x == 0) {
    float s = 0.f;
    for (int bb = 0; bb < 16; bb++) s += sh[bb];
    const float hpm = s * (1.f / 16.f);
    const float l8 = logf(1e-8f);
    const float p0 = 0.2f, p1 = 0.16f, p2 = 0.128f, p3 = 0.1024f;
    const float kl = p0 * (logf(p0) - l8)
                   + p1 * (logf(p1) - l8)
                   + p2 * (logf(p2) - logf(hpm + 1e-8f))
                   + p3 * (logf(p3) - logf(1.f + 1e-8f));
    out[0] = kl * 0.25f;
  }
}

// out_mp init: O = hp[b]*h  (4 rows / 256-thr block)
__global__ __launch_bounds__(256)
void k_outmp(const bf16_t* __restrict__ Hm, const float* __restrict__ HP,
             bf16_t* __restrict__ O) {
  const long long s = (long long)blockIdx.x * 4 + (threadIdx.x >> 6);
  const int d0 = (threadIdx.x & 63) * 4;
  const int b = (int)(s >> 10);
  const float hp = HP[b];
  const bf16x4 hv = *(const bf16x4*)(Hm + s * 256 + d0);
  bf16x4 ov;
#pragma unroll
  for (int e = 0; e < 4; e++) ov[e] = (bf16_t)(hp * (float)hv[e]);
  *(bf16x4*)(O + s * 256 + d0) = ov;
}

// ---------------------------------------------------------------------------
extern "C" void kernel_launch(void* const* d_in, const int* in_sizes, int n_in,
                              void* d_out, int out_size, void* d_ws, size_t ws_size,
                              hipStream_t stream) {
  (void)in_sizes; (void)n_in; (void)ws_size;
  const int*   x      = (const int*)d_in[0];
  const float* emb    = (const float*)d_in[1];
  const float* pos    = (const float*)d_in[2];
  const float* wih    = (const float*)d_in[3];
  const float* whh    = (const float*)d_in[4];
  const float* bih    = (const float*)d_in[5];
  const float* bhh    = (const float*)d_in[6];
  const float* lnp_g  = (const float*)d_in[7];
  const float* lnp_b  = (const float*)d_in[8];
  const float* sum_w  = (const float*)d_in[9];
  const float* sum_b  = (const float*)d_in[10];
  const float* msg_w1 = (const float*)d_in[11];
  const float* msg_b1 = (const float*)d_in[12];
  const float* msg_w2 = (const float*)d_in[13];
  const float* msg_b2 = (const float*)d_in[14];
  const float* upd_w1 = (const float*)d_in[15];
  const float* upd_b1 = (const float*)d_in[16];
  const float* upd_w2 = (const float*)d_in[17];
  const float* upd_b2 = (const float*)d_in[18];
  const float* halt_w = (const float*)d_in[19];
  const float* halt_b = (const float*)d_in[20];
  const float* lnm_g  = (const float*)d_in[21];
  const float* lnm_b  = (const float*)d_in[22];
  const float* q_b    = (const float*)d_in[24];
  const float* k_b    = (const float*)d_in[26];
  const float* v_b    = (const float*)d_in[28];
  const float* o_b    = (const float*)d_in[30];
  const float* bc_b   = (const float*)d_in[32];
  const float* lnf_g  = (const float*)d_in[33];
  const float* lnf_b  = (const float*)d_in[34];

  char* base = (char*)d_ws;
  size_t off = 0;
  auto alloc = [&](size_t bytes) -> void* {
    void* p = (void*)(base + off);
    off += (bytes + 255) & ~(size_t)255;
    return p;
  };
  const size_t SL2 = 16384ull * 256 * 2;   // bf16 activation slab (8 MiB)
  bf16_t* WIHT  = (bf16_t*)alloc(768 * 256 * 2);
  bf16_t* WHHT  = (bf16_t*)alloc(768 * 256 * 2);
  bf16_t* SUMT  = (bf16_t*)alloc(256 * 256 * 2);
  bf16_t* MW    = (bf16_t*)alloc(512 * 256 * 2);   // [msgW1self; msgW1neigh]
  bf16_t* UW1HT = (bf16_t*)alloc(256 * 256 * 2);   // upd_w1 hidden part (Bt form)
  bf16_t* W2T   = (bf16_t*)alloc(256 * 256 * 2);
  bf16_t* W2NT  = (bf16_t*)alloc(256 * 256 * 2);   // msg_w2 direct (row-major)
  bf16_t* UW1MT = (bf16_t*)alloc(256 * 256 * 2);
  bf16_t* UW2T  = (bf16_t*)alloc(256 * 256 * 2);
  bf16_t* WCB   = (bf16_t*)alloc(256 * 256 * 2);   // (msg_w2 @ uw1m) in Bt form
  bf16_t* QKVW  = (bf16_t*)alloc(768 * 256 * 2);
  bf16_t* OT    = (bf16_t*)alloc(256 * 256 * 2);
  bf16_t* BCT   = (bf16_t*)alloc(256 * 256 * 2);
  bf16_t* HEADT = (bf16_t*)alloc(256 * 256 * 2);
  float*  BIAS3 = (float*)alloc(768 * 4);
  float*  QKVB  = (float*)alloc(768 * 4);
  bf16_t* XE    = (bf16_t*)alloc(1024ull * 256 * 2);
  bf16_t* GITAB = (bf16_t*)alloc(1024ull * 768 * 2);
  bf16_t* LOCb  = (bf16_t*)alloc(65536ull * 256 * 2);        // 32 MiB

  // --- 64 MiB overlay: GRU {GH,H} / phase-B {SUMB} / MP {A3} / SCORES ------
  char*   SCR   = (char*)alloc(16ull * 1024 * 1024 * 4);     // 64 MiB
  bf16_t* SCORES = (bf16_t*)SCR;                             // 32 MiB (retrieval)
  bf16_t* GH    = (bf16_t*)SCR;                              // 24 MiB (GRU)
  bf16_t* H     = (bf16_t*)(SCR + 25165824);                 //  8 MiB (GRU)
  bf16_t* SUMB  = (bf16_t*)(SCR + 33554432);                 //  8 MiB (phase B)
  bf16_t* A3    = (bf16_t*)(SCR + 41943040);                 // 16 MiB (MP rounds)

  bf16_t* HMP   = (bf16_t*)alloc(SL2);
  bf16_t* G     = (bf16_t*)alloc(SL2);
  bf16_t* BROAD = (bf16_t*)alloc(SL2);
  bf16_t* UB    = (bf16_t*)alloc(SL2);   // later ATT
  bf16_t* U2B   = (bf16_t*)alloc(SL2);   // COMB
  bf16_t* OUTMP = (bf16_t*)alloc(SL2);
  bf16_t* QKV   = (bf16_t*)alloc(16384ull * 768 * 2);        // 24 MiB
  float*  PS    = (float*)alloc(512ull * 256 * 4);
  float*  HP    = (float*)alloc(64);
  bf16_t* ATT   = UB;
  bf16_t* COMB  = U2B;
  float*  out   = (float*)d_out;
  float*  klout = out + (out_size - 1);

  // 1) prep: transposes + xe + fused biases
  PrepArgs pa;
  pa.d[0]  = { wih,                    WIHT,            768, 0,   768 };
  pa.d[1]  = { whh,                    WHHT,            768, 0,   768 };
  pa.d[2]  = { sum_w,                  SUMT,            256, 0,   256 };
  pa.d[3]  = { msg_w1,                 MW,              256, 0,   256 };
  pa.d[4]  = { msg_w1,                 MW + 256 * 256,  256, 256, 256 };
  pa.d[5]  = { upd_w1,                 UW1HT,           256, 0,   256 };
  pa.d[6]  = { msg_w2,                 W2T,             256, 0,   256 };
  pa.d[7]  = { upd_w1,                 UW1MT,           256, 256, 256 };
  pa.d[8]  = { upd_w2,                 UW2T,            256, 0,   256 };
  pa.d[9]  = { (const float*)d_in[23], QKVW,            256, 0,   256 };
  pa.d[10] = { (const float*)d_in[25], QKVW + 256*256,  256, 0,   256 };
  pa.d[11] = { (const float*)d_in[27], QKVW + 512*256,  256, 0,   256 };
  pa.d[12] = { (const float*)d_in[29], OT,              256, 0,   256 };
  pa.d[13] = { (const float*)d_in[31], BCT,             256, 0,   256 };
  pa.d[14] = { (const float*)d_in[35], HEADT,           256, 0,   256 };
  pa.d[15] = { msg_w2,                 W2NT,            256, -1,  256 };
  pa.emb = emb; pa.pos = pos; pa.XE = XE;
  pa.msg_b1 = msg_b1; pa.msg_b2 = msg_b2; pa.upd_w1 = upd_w1; pa.upd_b1 = upd_b1;
  pa.q_b = q_b; pa.k_b = k_b; pa.v_b = v_b;
  pa.BIAS3 = BIAS3; pa.QKVB = QKVB;
  k_prep<<<dim3(1024, 18), 256, 0, stream>>>(pa);

  // 1b) WCB[j][i] = sum_k uw1m[k][j] * msg_w2[i][k]  (Bt form of msg_w2@uw1m)
  gemm64<0><<<dim3(4, 4), 256, 0, stream>>>(
      UW1MT, W2NT, WCB, nullptr, nullptr, 256, 256, 256, 0);

  // 2) GRU input table (bf16): gi = (emb+pos) @ wih + bih
  gemm64<GF_BIAS><<<dim3(16, 12), 256, 0, stream>>>(
      XE, WIHT, GITAB, bih, nullptr, 256, 256, 768, 0);

  // 3) GRU over 4 steps
  k_gru_gate<<<4096, 256, 0, stream>>>(x, GITAB, GH, bhh, H, LOCb, 0);
  for (int t = 1; t < 4; t++) {
    gemm_bt<GF_BIAS><<<dim3(128, 6), 256, 0, stream>>>(
        H, WHHT, GH, bhh, nullptr, 256, 256, 768, 0);
    k_gru_gate<<<4096, 256, 0, stream>>>(x, GITAB, GH, bhh, H, LOCb, t);
  }

  // 4) local = LN(gout) in place + patch means; summaries GEMM
  k_lnp4<<<4096, 256, 0, stream>>>(LOCb, SUMB, lnp_g, lnp_b);
  gemm64<GF_BIAS><<<dim3(256, 4), 256, 0, stream>>>(
      SUMB, SUMT, HMP, sum_b, nullptr, 256, 256, 256, 0);

  // 5) message-passing rounds (WC fusion + K512 dual-A UB GEMM + GEMM-LN)
  for (int step = 0; step < 4; step++) {
    gemm_bt<GF_BIAS><<<dim3(128, 4), 256, 0, stream>>>(
        HMP, MW, A3, BIAS3, nullptr, 256, 256, 512, 0);
    k_gelumix<<<4096, 256, 0, stream>>>(A3, G);
    gemm64_k512<<<dim3(256, 4), 256, 0, stream>>>(
        G, HMP, WCB, UW1HT, UB, BIAS3 + 512);
    if (step == 3) {
      gemm_ln<1><<<512, 256, 0, stream>>>(
          UB, UW2T, HMP, upd_b2, lnm_g, lnm_b, OUTMP, HP);
    } else {
      gemm_ln<0><<<512, 256, 0, stream>>>(
          UB, UW2T, HMP, upd_b2, lnm_g, lnm_b, nullptr, nullptr);
      if (step == 2) {
        k_halt1<<<dim3(32, 16), 64, 0, stream>>>(HMP, PS);
        k_halt2kl<<<1, 1024, 0, stream>>>(PS, halt_w, halt_b, HP, klout);
        k_outmp<<<4096, 256, 0, stream>>>(HMP, HP, OUTMP);
      }
    }
  }

  // 6) retrieval: QKV; causal scores GEMM (bf16 -> SCR); u64 top-8 scan
  gemm_bt<GF_BIAS><<<dim3(128, 6), 256, 0, stream>>>(
      OUTMP, QKVW, QKV, QKVB, nullptr, 256, 256, 768, 0);
  gemm_sc<<<dim3(8, 8, 16), 256, 0, stream>>>(QKV, QKV + 256, SCORES);
  k_topk<<<dim3(256, 16), 256, 0, stream>>>(SCORES, QKV, ATT);
  gemm64<GF_BIAS | GF_RES><<<dim3(256, 4), 256, 0, stream>>>(
      ATT, OT, COMB, o_b, OUTMP, 256, 256, 256, 256);
  gemm64<GF_BIAS><<<dim3(256, 4), 256, 0, stream>>>(
      COMB, BCT, BROAD, bc_b, nullptr, 256, 256, 256, 0);

  // 7) final = LN(local + broad) in place; logits = final @ head_w (f32 out)
  k_ln<<<16384, 256, 0, stream>>>(LOCb, BROAD, 2, LOCb, lnf_g, lnf_b);
  gemm_bt<GF_F32OUT><<<dim3(512, 2), 256, 0, stream>>>(
      LOCb, HEADT, out, nullptr, nullptr, 256, 256, 256, 0);
}